// Round 2
// baseline (1386.498 us; speedup 1.0000x reference)
//
#include <hip/hip_runtime.h>

#define N_NODES 65536
#define NSEG    128

using s16x8 = __attribute__((ext_vector_type(8))) short;
using s16x4 = __attribute__((ext_vector_type(4))) short;
using f32x4 = __attribute__((ext_vector_type(4))) float;

__device__ __forceinline__ float bf2f(unsigned short s) {
    union { unsigned u; float f; } x; x.u = ((unsigned)s) << 16; return x.f;
}
__device__ __forceinline__ short f2bf(float f) {
    union { float f; unsigned u; } x; x.f = f;
    unsigned r = x.u + 0x7FFFu + ((x.u >> 16) & 1u);
    return (short)(r >> 16);
}
__device__ __forceinline__ void gload_lds16(const void* g, void* lds) {
    __builtin_amdgcn_global_load_lds((const __attribute__((address_space(1))) void*)g,
                                     (__attribute__((address_space(3))) void*)lds, 16, 0, 0);
}

// ---------------- prep kernels ----------------

__global__ void prep_sm_kernel(const float* __restrict__ score, const float* __restrict__ pos,
                               short* __restrict__ sm) {
    int i = blockIdx.x * blockDim.x + threadIdx.x;   // one thread per 4 elements
    int base = i * 4;
    f32x4 s = *(const f32x4*)(score + base);
    f32x4 p = *(const f32x4*)(pos + (base & 255));
    s16x4 o;
#pragma unroll
    for (int j = 0; j < 4; ++j) o[j] = f2bf(s[j] + p[j]);
    *(s16x4*)(sm + base) = o;
}

// fp32 [U][R][C] -> bf16 [U][C][R]; R,C multiples of 32
__global__ void transpose_cast_kernel(const float* __restrict__ in, short* __restrict__ out,
                                      int R, int C) {
    const int u = blockIdx.z;
    in  += (long)u * R * C;
    out += (long)u * R * C;
    __shared__ float t[32][33];
    const int c0 = blockIdx.x * 32, r0 = blockIdx.y * 32;
    const int tx = threadIdx.x & 31, ty = threadIdx.x >> 5;   // 32 x 8
#pragma unroll
    for (int i = 0; i < 32; i += 8)
        t[ty + i][tx] = in[(r0 + ty + i) * C + c0 + tx];
    __syncthreads();
#pragma unroll
    for (int i = 0; i < 32; i += 8)
        out[(long)(c0 + ty + i) * R + r0 + tx] = f2bf(t[tx][ty + i]);
}

__global__ void prep_small_kernel(const float* __restrict__ bq1, const float* __restrict__ bk1,
                                  const float* __restrict__ bv1, const float* __restrict__ bq2,
                                  const float* __restrict__ bk2, const float* __restrict__ bv2,
                                  const float* __restrict__ bo2, const float* __restrict__ para,
                                  float* __restrict__ b1cat, float* __restrict__ b2cat,
                                  float* __restrict__ bo2p) {
    int i = blockIdx.x * blockDim.x + threadIdx.x;
    if (i < 6144) {
        int u = i >> 8, j = i & 255;
        const float* s = (u < 8) ? (bq1 + u * 256 + j)
                       : (u < 16) ? (bk1 + (u - 8) * 256 + j)
                                  : (bv1 + (u - 16) * 256 + j);
        b1cat[i] = *s;
    } else if (i < 9216) {
        int ii = i - 6144;
        int u = ii >> 7, j = ii & 127;
        const float* s = (u < 8) ? (bq2 + u * 128 + j)
                       : (u < 16) ? (bk2 + (u - 8) * 128 + j)
                                  : (bv2 + (u - 16) * 128 + j);
        b2cat[ii] = *s;
    } else if (i < 9344) {
        int e = i - 9216;
        bo2p[e] = bo2[e] + para[e];
    }
}

// ---------------- MFMA GEMM: C[M,cols] = act(A[M,K] * B^T[cols,K] + bias) ----------------
// 128x128 tile, BK=64, 4 waves (2x2), 16x16x32 bf16 MFMA.
// LDS staged via global_load_lds(16B) with XOR-swizzled global source (rule #21:
// linear LDS dest + inverse-swizzled source + same swizzle on read).

template <bool RELU, bool OUTBF16>
__global__ __launch_bounds__(256, 2)
void gemm_bt(const short* __restrict__ A, int lda,
             const short* __restrict__ B,           // [cols][K]
             const float* __restrict__ bias,
             void* __restrict__ Cv, int ldc, int K) {
    __shared__ __align__(16) short As[128 * 64];
    __shared__ __align__(16) short Bs[128 * 64];
    const int tid  = threadIdx.x;
    const int lane = tid & 63;
    const int wave = tid >> 6;
    const int wm = wave >> 1, wn = wave & 1;
    const int brow = blockIdx.x * 128;
    const int bcol = blockIdx.y * 128;

    f32x4 acc[4][4];
#pragma unroll
    for (int i = 0; i < 4; ++i)
#pragma unroll
        for (int j = 0; j < 4; ++j) acc[i][j] = (f32x4){0.f, 0.f, 0.f, 0.f};

    const int lrow = lane >> 3;                 // 0..7 (row within 8-row chunk block)
    const int schk = ((lane & 7) ^ lrow) * 8;   // swizzled 16B-chunk (in shorts)

    const short* aptr[4];
    const short* bptr[4];
#pragma unroll
    for (int i = 0; i < 4; ++i) {
        int c = wave * 4 + i;
        int r = c * 8 + lrow;
        aptr[i] = A + (long)(brow + r) * lda + schk;
        bptr[i] = B + (long)(bcol + r) * K + schk;
    }

    for (int kt = 0; kt < K; kt += 64) {
        __syncthreads();                         // prior tile's reads done
#pragma unroll
        for (int i = 0; i < 4; ++i) {
            int c = wave * 4 + i;
            gload_lds16(aptr[i] + kt, &As[c * 512]);
        }
#pragma unroll
        for (int i = 0; i < 4; ++i) {
            int c = wave * 4 + i;
            gload_lds16(bptr[i] + kt, &Bs[c * 512]);
        }
        __syncthreads();                         // staging visible (vmcnt drained)
#pragma unroll
        for (int kk = 0; kk < 2; ++kk) {
            const int slot = (((kk * 4) + (lane >> 4)) ^ (lane & 7)) * 8;
            s16x8 af[4], bfv[4];
#pragma unroll
            for (int i = 0; i < 4; ++i)
                af[i] = *(const s16x8*)&As[(wm * 64 + i * 16 + (lane & 15)) * 64 + slot];
#pragma unroll
            for (int j = 0; j < 4; ++j)
                bfv[j] = *(const s16x8*)&Bs[(wn * 64 + j * 16 + (lane & 15)) * 64 + slot];
#pragma unroll
            for (int i = 0; i < 4; ++i)
#pragma unroll
                for (int j = 0; j < 4; ++j)
                    acc[i][j] = __builtin_amdgcn_mfma_f32_16x16x32_bf16(af[i], bfv[j], acc[i][j], 0, 0, 0);
        }
    }

    // epilogue: C/D layout col=lane&15, row=(lane>>4)*4+reg (m89-verified)
    const int c0 = lane & 15;
    const int r0 = (lane >> 4) * 4;
#pragma unroll
    for (int j = 0; j < 4; ++j) {
        int col = bcol + wn * 64 + j * 16 + c0;
        float bv = bias[col];
#pragma unroll
        for (int i = 0; i < 4; ++i) {
            int row = brow + wm * 64 + i * 16 + r0;
#pragma unroll
            for (int r = 0; r < 4; ++r) {
                float v = acc[i][j][r] + bv;
                if (RELU) v = fmaxf(v, 0.f);
                if (OUTBF16) ((short*)Cv)[(long)(row + r) * ldc + col] = f2bf(v);
                else         ((float*)Cv)[(long)(row + r) * ldc + col] = v;
            }
        }
    }
}

// ---------------- attention kernels ----------------

// scores[n, h*8+g] = (q[n,h,:] . k[n,g,:]) / sqrt(128);  q,k are [nc,1024] bf16 (chunk-local)
__global__ void scores_kernel(const short* __restrict__ q, const short* __restrict__ k,
                              float* __restrict__ scores, int nc) {
    int gtid = blockIdx.x * blockDim.x + threadIdx.x;
    int wid = gtid >> 6, lane = gtid & 63;
    int nw = (gridDim.x * blockDim.x) >> 6;
    int h = lane >> 3, g = lane & 7;
    for (int n = wid; n < nc; n += nw) {
        const short* qp = q + (long)n * 1024 + h * 128;
        const short* kp = k + (long)n * 1024 + g * 128;
        float acc = 0.f;
#pragma unroll
        for (int c = 0; c < 16; ++c) {
            s16x8 qv = *(const s16x8*)(qp + c * 8);
            s16x8 kv = *(const s16x8*)(kp + c * 8);
#pragma unroll
            for (int j = 0; j < 8; ++j)
                acc += bf2f((unsigned short)qv[j]) * bf2f((unsigned short)kv[j]);
        }
        scores[(long)n * 64 + lane] = acc * 0.08838834764831845f;  // 1/sqrt(128)
    }
}

// one block per segment; batch sorted -> binary search range; two-pass max then sum(exp)
__global__ void segstats_kernel(const float* __restrict__ scores, const int* __restrict__ batch,
                                float* __restrict__ segm, float* __restrict__ segdinv) {
    const int g = blockIdx.x;
    int lo = 0, hi = N_NODES;
    while (lo < hi) { int mid = (lo + hi) >> 1; if (batch[mid] < g) lo = mid + 1; else hi = mid; }
    const int start = lo;
    hi = N_NODES;
    while (lo < hi) { int mid = (lo + hi) >> 1; if (batch[mid] <= g) lo = mid + 1; else hi = mid; }
    const int end = lo;

    const int e = threadIdx.x & 63, sub = threadIdx.x >> 6;
    __shared__ float red[4][64];
    float m = -1e30f;
    for (int n = start + sub; n < end; n += 4)
        m = fmaxf(m, scores[(long)n * 64 + e]);
    red[sub][e] = m;
    __syncthreads();
    m = fmaxf(fmaxf(red[0][e], red[1][e]), fmaxf(red[2][e], red[3][e]));
    __syncthreads();
    float s = 0.f;
    for (int n = start + sub; n < end; n += 4)
        s += expf(scores[(long)n * 64 + e] - m);
    red[sub][e] = s;
    __syncthreads();
    if (sub == 0) {
        float den = red[0][e] + red[1][e] + red[2][e] + red[3][e] + 1e-16f;
        segm[g * 64 + e]    = m;
        segdinv[g * 64 + e] = 1.f / den;
    }
}

// s[nl, h*128+e] = sum_g aw[n,h,g] * v[nl,g,e]; v,s chunk-local [nc,1024]; scores/batch global via n0
__global__ void pv_kernel(const short* __restrict__ v, short* __restrict__ sout,
                          const float* __restrict__ scores, const int* __restrict__ batch,
                          const float* __restrict__ segm, const float* __restrict__ segdinv,
                          int n0) {
    __shared__ float aw[16][64];
    const int t = threadIdx.x;
    const int nodeL0 = blockIdx.x * 16;          // chunk-local node base
    {
        int j0 = t * 4;
        int nl = j0 >> 6, e0 = j0 & 63;
        int n = n0 + nodeL0 + nl;                // global node
        int b = batch[n];
        f32x4 sc = *(const f32x4*)(scores + (long)n * 64 + e0);
#pragma unroll
        for (int i = 0; i < 4; ++i)
            aw[nl][e0 + i] = expf(sc[i] - segm[b * 64 + e0 + i]) * segdinv[b * 64 + e0 + i];
    }
    __syncthreads();
    const int nl = t >> 4;
    const int ec = (t & 15) * 8;
    const long nloc = nodeL0 + nl;
    const short* vp = v + nloc * 1024 + ec;
    float acc[8][8];
#pragma unroll
    for (int h = 0; h < 8; ++h)
#pragma unroll
        for (int j = 0; j < 8; ++j) acc[h][j] = 0.f;
#pragma unroll
    for (int g = 0; g < 8; ++g) {
        s16x8 vv = *(const s16x8*)(vp + g * 128);
        float vf[8];
#pragma unroll
        for (int j = 0; j < 8; ++j) vf[j] = bf2f((unsigned short)vv[j]);
#pragma unroll
        for (int h = 0; h < 8; ++h) {
            float wgt = aw[nl][h * 8 + g];
#pragma unroll
            for (int j = 0; j < 8; ++j) acc[h][j] += wgt * vf[j];
        }
    }
#pragma unroll
    for (int h = 0; h < 8; ++h) {
        s16x8 o;
#pragma unroll
        for (int j = 0; j < 8; ++j) o[j] = f2bf(acc[h][j]);
        *(s16x8*)(sout + nloc * 1024 + h * 128 + ec) = o;
    }
}

// ---------------- launch ----------------

extern "C" void kernel_launch(void* const* d_in, const int* in_sizes, int n_in,
                              void* d_out, int out_size, void* d_ws, size_t ws_size,
                              hipStream_t stream) {
    const float* score = (const float*)d_in[0];
    const int*   batch = (const int*)d_in[2];
    const float* pos   = (const float*)d_in[3];
    const float* para  = (const float*)d_in[4];
    const float* Wq1 = (const float*)d_in[5];
    const float* bq1 = (const float*)d_in[6];
    const float* Wq2 = (const float*)d_in[7];
    const float* bq2 = (const float*)d_in[8];
    const float* Wk1 = (const float*)d_in[9];
    const float* bk1 = (const float*)d_in[10];
    const float* Wk2 = (const float*)d_in[11];
    const float* bk2 = (const float*)d_in[12];
    const float* Wv1 = (const float*)d_in[13];
    const float* bv1 = (const float*)d_in[14];
    const float* Wv2 = (const float*)d_in[15];
    const float* bv2 = (const float*)d_in[16];
    const float* Wo1 = (const float*)d_in[17];
    const float* bo1 = (const float*)d_in[18];
    const float* Wo2 = (const float*)d_in[19];
    const float* bo2 = (const float*)d_in[20];
    float* out = (float*)d_out;
    (void)in_sizes; (void)n_in; (void)out_size;

    // ---- persistent region (~56 MB) ----
    char* w = (char*)d_ws;
    short* sm     = (short*)w; w += (size_t)N_NODES * 256 * 2;       // 33.5 MB
    float* scoresb= (float*)w; w += (size_t)N_NODES * 64 * 4;        // 16.8 MB
    short* W1T    = (short*)w; w += (size_t)24 * 256 * 256 * 2;      // 3.1 MB
    short* W2T    = (short*)w; w += (size_t)24 * 128 * 256 * 2;      // 1.6 MB
    short* Wo1T   = (short*)w; w += (size_t)256 * 1024 * 2;          // 0.5 MB
    short* Wo2T   = (short*)w; w += (size_t)128 * 256 * 2;
    float* b1cat  = (float*)w; w += 6144 * 4;
    float* b2cat  = (float*)w; w += 3072 * 4;
    float* bo2p   = (float*)w; w += 1024;
    float* segm   = (float*)w; w += 8192 * 4;
    float* segdi  = (float*)w; w += 8192 * 4;
    size_t persist = (size_t)(w - (char*)d_ws);

    // ---- chunked region: pick largest chunk that fits ----
    int NC = N_NODES;  // per-chunk bytes = NC*4608 (c1h2: NC*512, X: NC*2048, Y: NC*2048)
    while (NC > 8192 && persist + (size_t)NC * 4608 > ws_size) NC >>= 1;
    const int nchunks = N_NODES / NC;
    short* c1h2 = (short*)w;                       // [NC,256]
    short* X    = (short*)(w + (size_t)NC * 512);  // [NC,1024]  q, later v
    short* Y    = (short*)(w + (size_t)NC * 512 + (size_t)NC * 2048); // [NC,1024] k, later s

    // ---- prep ----
    prep_sm_kernel<<<N_NODES * 256 / 4 / 256, 256, 0, stream>>>(score, pos, sm);
    transpose_cast_kernel<<<dim3(8, 8, 8), 256, 0, stream>>>(Wq1, W1T,              256, 256);
    transpose_cast_kernel<<<dim3(8, 8, 8), 256, 0, stream>>>(Wk1, W1T + 8  * 65536, 256, 256);
    transpose_cast_kernel<<<dim3(8, 8, 8), 256, 0, stream>>>(Wv1, W1T + 16 * 65536, 256, 256);
    transpose_cast_kernel<<<dim3(4, 8, 8), 256, 0, stream>>>(Wq2, W2T,              256, 128);
    transpose_cast_kernel<<<dim3(4, 8, 8), 256, 0, stream>>>(Wk2, W2T + 8  * 32768, 256, 128);
    transpose_cast_kernel<<<dim3(4, 8, 8), 256, 0, stream>>>(Wv2, W2T + 16 * 32768, 256, 128);
    transpose_cast_kernel<<<dim3(8, 32, 1), 256, 0, stream>>>(Wo1, Wo1T, 1024, 256);
    transpose_cast_kernel<<<dim3(4, 8, 1), 256, 0, stream>>>(Wo2, Wo2T,  256, 128);
    prep_small_kernel<<<37, 256, 0, stream>>>(bq1, bk1, bv1, bq2, bk2, bv2, bo2, para,
                                              b1cat, b2cat, bo2p);

    // ---- phase A: q,k + scores, per chunk ----
    for (int c = 0; c < nchunks; ++c) {
        const int n0 = c * NC;
        const short* smc = sm + (size_t)n0 * 256;
        for (int u = 0; u < 16; ++u) {          // u<8: q-heads, u>=8: k-heads
            short* dst = (u < 8) ? (X + u * 128) : (Y + (u - 8) * 128);
            gemm_bt<true,  true><<<dim3(NC / 128, 2), 256, 0, stream>>>(
                smc, 256, W1T + u * 65536, b1cat + u * 256, c1h2, 256, 256);
            gemm_bt<false, true><<<dim3(NC / 128, 1), 256, 0, stream>>>(
                c1h2, 256, W2T + u * 32768, b2cat + u * 128, dst, 1024, 256);
        }
        scores_kernel<<<2048, 256, 0, stream>>>(X, Y, scoresb + (size_t)n0 * 64, NC);
    }

    // ---- segment softmax stats (global) ----
    segstats_kernel<<<NSEG, 256, 0, stream>>>(scoresb, batch, segm, segdi);

    // ---- phase B: v + PV + out-MLP, per chunk ----
    for (int c = 0; c < nchunks; ++c) {
        const int n0 = c * NC;
        const short* smc = sm + (size_t)n0 * 256;
        for (int u = 16; u < 24; ++u) {         // v-heads
            gemm_bt<true,  true><<<dim3(NC / 128, 2), 256, 0, stream>>>(
                smc, 256, W1T + u * 65536, b1cat + u * 256, c1h2, 256, 256);
            gemm_bt<false, true><<<dim3(NC / 128, 1), 256, 0, stream>>>(
                c1h2, 256, W2T + u * 32768, b2cat + u * 128, X + (u - 16) * 128, 1024, 256);
        }
        pv_kernel<<<NC / 16, 256, 0, stream>>>(X, Y, scoresb, batch, segm, segdi, n0);
        gemm_bt<true,  true><<<dim3(NC / 128, 2), 256, 0, stream>>>(
            Y, 1024, Wo1T, bo1, c1h2, 256, 1024);
        gemm_bt<false, false><<<dim3(NC / 128, 1), 256, 0, stream>>>(
            c1h2, 256, Wo2T, bo2p, out + (size_t)n0 * 128, 128, 256);
    }
}

// Round 3
// 910.498 us; speedup vs baseline: 1.5228x; 1.5228x over previous
//
#include <hip/hip_runtime.h>

#define N_NODES 65536
#define NSEG    128

using s16x8 = __attribute__((ext_vector_type(8))) short;
using s16x4 = __attribute__((ext_vector_type(4))) short;
using f32x4 = __attribute__((ext_vector_type(4))) float;

__device__ __forceinline__ float bf2f(unsigned short s) {
    union { unsigned u; float f; } x; x.u = ((unsigned)s) << 16; return x.f;
}
__device__ __forceinline__ short f2bf(float f) {
    union { float f; unsigned u; } x; x.f = f;
    unsigned r = x.u + 0x7FFFu + ((x.u >> 16) & 1u);
    return (short)(r >> 16);
}
__device__ __forceinline__ void gload_lds16(const void* g, void* lds) {
    __builtin_amdgcn_global_load_lds((const __attribute__((address_space(1))) void*)g,
                                     (__attribute__((address_space(3))) void*)lds, 16, 0, 0);
}

// ---------------- prep kernels ----------------

__global__ void prep_sm_kernel(const float* __restrict__ score, const float* __restrict__ pos,
                               short* __restrict__ sm) {
    int i = blockIdx.x * blockDim.x + threadIdx.x;
    int base = i * 4;
    f32x4 s = *(const f32x4*)(score + base);
    f32x4 p = *(const f32x4*)(pos + (base & 255));
    s16x4 o;
#pragma unroll
    for (int j = 0; j < 4; ++j) o[j] = f2bf(s[j] + p[j]);
    *(s16x4*)(sm + base) = o;
}

// fp32 [U][R][C] -> bf16 [U][C][R]; R,C multiples of 32
__global__ void transpose_cast_kernel(const float* __restrict__ in, short* __restrict__ out,
                                      int R, int C) {
    const int u = blockIdx.z;
    in  += (long)u * R * C;
    out += (long)u * R * C;
    __shared__ float t[32][33];
    const int c0 = blockIdx.x * 32, r0 = blockIdx.y * 32;
    const int tx = threadIdx.x & 31, ty = threadIdx.x >> 5;
#pragma unroll
    for (int i = 0; i < 32; i += 8)
        t[ty + i][tx] = in[(r0 + ty + i) * C + c0 + tx];
    __syncthreads();
#pragma unroll
    for (int i = 0; i < 32; i += 8)
        out[(long)(c0 + ty + i) * R + r0 + tx] = f2bf(t[tx][ty + i]);
}

__global__ void prep_small_kernel(const float* __restrict__ bq1, const float* __restrict__ bk1,
                                  const float* __restrict__ bv1, const float* __restrict__ bq2,
                                  const float* __restrict__ bk2, const float* __restrict__ bv2,
                                  const float* __restrict__ bo2, const float* __restrict__ para,
                                  float* __restrict__ b1cat, float* __restrict__ b2cat,
                                  float* __restrict__ bo2p) {
    int i = blockIdx.x * blockDim.x + threadIdx.x;
    if (i < 6144) {
        int u = i >> 8, j = i & 255;
        const float* s = (u < 8) ? (bq1 + u * 256 + j)
                       : (u < 16) ? (bk1 + (u - 8) * 256 + j)
                                  : (bv1 + (u - 16) * 256 + j);
        b1cat[i] = *s;
    } else if (i < 9216) {
        int ii = i - 6144;
        int u = ii >> 7, j = ii & 127;
        const float* s = (u < 8) ? (bq2 + u * 128 + j)
                       : (u < 16) ? (bk2 + (u - 8) * 128 + j)
                                  : (bv2 + (u - 16) * 128 + j);
        b2cat[ii] = *s;
    } else if (i < 9344) {
        int e = i - 9216;
        bo2p[e] = bo2[e] + para[e];
    }
}

// ------- MFMA GEMM, unit-batched over blockIdx.z -------
// C_u[M,cols] = act(A_u[M,K] * B_u^T[cols,K] + bias_u); 128x128 tile, BK=64,
// 4 waves (2x2), 16x16x32 bf16. LDS via global_load_lds(16B), XOR-swizzled
// source + same swizzle on read (rule #21).

template <bool RELU, bool OUTBF16>
__global__ __launch_bounds__(256, 2)
void gemm_bt_z(const short* __restrict__ A, int lda, long a_ustride,
               const short* __restrict__ B, long b_ustride,
               const float* __restrict__ bias, int bias_ustride,
               void* __restrict__ Cv, int ldc, long c_ustride, int K) {
    const int u = blockIdx.z;
    A    += (long)u * a_ustride;
    B    += (long)u * b_ustride;
    bias += (long)u * bias_ustride;

    __shared__ __align__(16) short As[128 * 64];
    __shared__ __align__(16) short Bs[128 * 64];
    const int tid  = threadIdx.x;
    const int lane = tid & 63;
    const int wave = tid >> 6;
    const int wm = wave >> 1, wn = wave & 1;
    const int brow = blockIdx.x * 128;
    const int bcol = blockIdx.y * 128;

    f32x4 acc[4][4];
#pragma unroll
    for (int i = 0; i < 4; ++i)
#pragma unroll
        for (int j = 0; j < 4; ++j) acc[i][j] = (f32x4){0.f, 0.f, 0.f, 0.f};

    const int lrow = lane >> 3;
    const int schk = ((lane & 7) ^ lrow) * 8;

    const short* aptr[4];
    const short* bptr[4];
#pragma unroll
    for (int i = 0; i < 4; ++i) {
        int c = wave * 4 + i;
        int r = c * 8 + lrow;
        aptr[i] = A + (long)(brow + r) * lda + schk;
        bptr[i] = B + (long)(bcol + r) * K + schk;
    }

    for (int kt = 0; kt < K; kt += 64) {
        __syncthreads();
#pragma unroll
        for (int i = 0; i < 4; ++i) {
            int c = wave * 4 + i;
            gload_lds16(aptr[i] + kt, &As[c * 512]);
        }
#pragma unroll
        for (int i = 0; i < 4; ++i) {
            int c = wave * 4 + i;
            gload_lds16(bptr[i] + kt, &Bs[c * 512]);
        }
        __syncthreads();
#pragma unroll
        for (int kk = 0; kk < 2; ++kk) {
            const int slot = (((kk * 4) + (lane >> 4)) ^ (lane & 7)) * 8;
            s16x8 af[4], bfv[4];
#pragma unroll
            for (int i = 0; i < 4; ++i)
                af[i] = *(const s16x8*)&As[(wm * 64 + i * 16 + (lane & 15)) * 64 + slot];
#pragma unroll
            for (int j = 0; j < 4; ++j)
                bfv[j] = *(const s16x8*)&Bs[(wn * 64 + j * 16 + (lane & 15)) * 64 + slot];
#pragma unroll
            for (int i = 0; i < 4; ++i)
#pragma unroll
                for (int j = 0; j < 4; ++j)
                    acc[i][j] = __builtin_amdgcn_mfma_f32_16x16x32_bf16(af[i], bfv[j], acc[i][j], 0, 0, 0);
        }
    }

    const int c0 = lane & 15;
    const int r0 = (lane >> 4) * 4;
#pragma unroll
    for (int j = 0; j < 4; ++j) {
        int col = bcol + wn * 64 + j * 16 + c0;
        float bv = bias[col];
#pragma unroll
        for (int i = 0; i < 4; ++i) {
            int row = brow + wm * 64 + i * 16 + r0;
#pragma unroll
            for (int r = 0; r < 4; ++r) {
                float v = acc[i][j][r] + bv;
                if (RELU) v = fmaxf(v, 0.f);
                if (OUTBF16) ((short*)Cv)[u * c_ustride + (long)(row + r) * ldc + col] = f2bf(v);
                else         ((float*)Cv)[u * c_ustride + (long)(row + r) * ldc + col] = v;
            }
        }
    }
}

// ---------------- attention kernels ----------------

// MFMA scores: qk chunk-local [nc,2048] (q cols 0..1023, k cols 1024..2047).
// One wave per node-pair: A rows 0-7 = q-heads of n0, 8-15 = q-heads of n1;
// B cols likewise from k. Valid D quadrants = per-node 8x8 score blocks.
__global__ void scores_mfma_kernel(const short* __restrict__ qk, float* __restrict__ scores,
                                   int nc) {
    const int lane = threadIdx.x & 63;
    int gw = (blockIdx.x * blockDim.x + threadIdx.x) >> 6;
    int nw = (gridDim.x * blockDim.x) >> 6;
    const int npairs = nc >> 1;
    const int r = lane & 15, ks = lane >> 4;
    for (int p = gw; p < npairs; p += nw) {
        const long n0 = (long)p * 2;
        const short* qp = qk + (n0 + (r >> 3)) * 2048 + (r & 7) * 128 + ks * 8;
        const short* kp = qp + 1024;
        f32x4 acc = (f32x4){0.f, 0.f, 0.f, 0.f};
#pragma unroll
        for (int kt = 0; kt < 4; ++kt) {
            s16x8 a = *(const s16x8*)(qp + kt * 32);
            s16x8 b = *(const s16x8*)(kp + kt * 32);
            acc = __builtin_amdgcn_mfma_f32_16x16x32_bf16(a, b, acc, 0, 0, 0);
        }
        const int c = lane & 15, rr0 = (lane >> 4) * 4;
        if ((rr0 >> 3) == (c >> 3)) {      // same-node quadrant
            float* o = scores + (n0 + (rr0 >> 3)) * 64 + (c & 7);
#pragma unroll
            for (int reg = 0; reg < 4; ++reg)
                o[((rr0 & 7) + reg) * 8] = acc[reg] * 0.08838834764831845f;
        }
    }
}

// one block per segment; batch sorted -> binary search range; two-pass max then sum(exp)
__global__ void segstats_kernel(const float* __restrict__ scores, const int* __restrict__ batch,
                                float* __restrict__ segm, float* __restrict__ segdinv) {
    const int g = blockIdx.x;
    int lo = 0, hi = N_NODES;
    while (lo < hi) { int mid = (lo + hi) >> 1; if (batch[mid] < g) lo = mid + 1; else hi = mid; }
    const int start = lo;
    hi = N_NODES;
    while (lo < hi) { int mid = (lo + hi) >> 1; if (batch[mid] <= g) lo = mid + 1; else hi = mid; }
    const int end = lo;

    const int e = threadIdx.x & 63, sub = threadIdx.x >> 6;
    __shared__ float red[4][64];
    float m = -1e30f;
    for (int n = start + sub; n < end; n += 4)
        m = fmaxf(m, scores[(long)n * 64 + e]);
    red[sub][e] = m;
    __syncthreads();
    m = fmaxf(fmaxf(red[0][e], red[1][e]), fmaxf(red[2][e], red[3][e]));
    __syncthreads();
    float s = 0.f;
    for (int n = start + sub; n < end; n += 4)
        s += expf(scores[(long)n * 64 + e] - m);
    red[sub][e] = s;
    __syncthreads();
    if (sub == 0) {
        float den = red[0][e] + red[1][e] + red[2][e] + red[3][e] + 1e-16f;
        segm[g * 64 + e]    = m;
        segdinv[g * 64 + e] = 1.f / den;
    }
}

// s[nl, h*128+e] = sum_g aw[n,h,g] * v[nl,g,e]
__global__ void pv_kernel(const short* __restrict__ v, short* __restrict__ sout,
                          const float* __restrict__ scores, const int* __restrict__ batch,
                          const float* __restrict__ segm, const float* __restrict__ segdinv,
                          int n0) {
    __shared__ float aw[16][64];
    const int t = threadIdx.x;
    const int nodeL0 = blockIdx.x * 16;
    {
        int j0 = t * 4;
        int nl = j0 >> 6, e0 = j0 & 63;
        int n = n0 + nodeL0 + nl;
        int b = batch[n];
        f32x4 sc = *(const f32x4*)(scores + (long)n * 64 + e0);
#pragma unroll
        for (int i = 0; i < 4; ++i)
            aw[nl][e0 + i] = expf(sc[i] - segm[b * 64 + e0 + i]) * segdinv[b * 64 + e0 + i];
    }
    __syncthreads();
    const int nl = t >> 4;
    const int ec = (t & 15) * 8;
    const long nloc = nodeL0 + nl;
    const short* vp = v + nloc * 1024 + ec;
    float acc[8][8];
#pragma unroll
    for (int h = 0; h < 8; ++h)
#pragma unroll
        for (int j = 0; j < 8; ++j) acc[h][j] = 0.f;
#pragma unroll
    for (int g = 0; g < 8; ++g) {
        s16x8 vv = *(const s16x8*)(vp + g * 128);
        float vf[8];
#pragma unroll
        for (int j = 0; j < 8; ++j) vf[j] = bf2f((unsigned short)vv[j]);
#pragma unroll
        for (int h = 0; h < 8; ++h) {
            float wgt = aw[nl][h * 8 + g];
#pragma unroll
            for (int j = 0; j < 8; ++j) acc[h][j] += wgt * vf[j];
        }
    }
#pragma unroll
    for (int h = 0; h < 8; ++h) {
        s16x8 o;
#pragma unroll
        for (int j = 0; j < 8; ++j) o[j] = f2bf(acc[h][j]);
        *(s16x8*)(sout + nloc * 1024 + h * 128 + ec) = o;
    }
}

// ---------------- launch ----------------

extern "C" void kernel_launch(void* const* d_in, const int* in_sizes, int n_in,
                              void* d_out, int out_size, void* d_ws, size_t ws_size,
                              hipStream_t stream) {
    const float* score = (const float*)d_in[0];
    const int*   batch = (const int*)d_in[2];
    const float* pos   = (const float*)d_in[3];
    const float* para  = (const float*)d_in[4];
    const float* Wq1 = (const float*)d_in[5];
    const float* bq1 = (const float*)d_in[6];
    const float* Wq2 = (const float*)d_in[7];
    const float* bq2 = (const float*)d_in[8];
    const float* Wk1 = (const float*)d_in[9];
    const float* bk1 = (const float*)d_in[10];
    const float* Wk2 = (const float*)d_in[11];
    const float* bk2 = (const float*)d_in[12];
    const float* Wv1 = (const float*)d_in[13];
    const float* bv1 = (const float*)d_in[14];
    const float* Wv2 = (const float*)d_in[15];
    const float* bv2 = (const float*)d_in[16];
    const float* Wo1 = (const float*)d_in[17];
    const float* bo1 = (const float*)d_in[18];
    const float* Wo2 = (const float*)d_in[19];
    const float* bo2 = (const float*)d_in[20];
    float* out = (float*)d_out;
    (void)in_sizes; (void)n_in; (void)out_size;

    // ---- persistent region (~56 MB) ----
    char* w = (char*)d_ws;
    short* sm     = (short*)w; w += (size_t)N_NODES * 256 * 2;
    float* scoresb= (float*)w; w += (size_t)N_NODES * 64 * 4;
    short* W1T    = (short*)w; w += (size_t)24 * 256 * 256 * 2;
    short* W2T    = (short*)w; w += (size_t)24 * 128 * 256 * 2;
    short* Wo1T   = (short*)w; w += (size_t)256 * 1024 * 2;
    short* Wo2T   = (short*)w; w += (size_t)128 * 256 * 2;
    float* b1cat  = (float*)w; w += 6144 * 4;
    float* b2cat  = (float*)w; w += 3072 * 4;
    float* bo2p   = (float*)w; w += 1024;
    float* segm   = (float*)w; w += 8192 * 4;
    float* segdi  = (float*)w; w += 8192 * 4;
    size_t persist = (size_t)(w - (char*)d_ws);
    size_t area = ws_size - persist;

    // phase A chunk: c1qk [16][NC,256] (NC*8192 B) + qk [NC,2048] (NC*4096 B)
    int NCA = 16384;
    while (NCA > 1024 && (size_t)NCA * 12288 > area) NCA >>= 1;
    // phase B chunk: c1v/h2 [8][NC,256] (NC*4096) + v [NC,1024] (NC*2048) + s (NC*2048)
    int NCB = 32768;
    while (NCB > 1024 && (size_t)NCB * 8192 > area) NCB >>= 1;

    // ---- prep ----
    prep_sm_kernel<<<N_NODES * 256 / 4 / 256, 256, 0, stream>>>(score, pos, sm);
    transpose_cast_kernel<<<dim3(8, 8, 8), 256, 0, stream>>>(Wq1, W1T,              256, 256);
    transpose_cast_kernel<<<dim3(8, 8, 8), 256, 0, stream>>>(Wk1, W1T + 8  * 65536, 256, 256);
    transpose_cast_kernel<<<dim3(8, 8, 8), 256, 0, stream>>>(Wv1, W1T + 16 * 65536, 256, 256);
    transpose_cast_kernel<<<dim3(4, 8, 8), 256, 0, stream>>>(Wq2, W2T,              256, 128);
    transpose_cast_kernel<<<dim3(4, 8, 8), 256, 0, stream>>>(Wk2, W2T + 8  * 32768, 256, 128);
    transpose_cast_kernel<<<dim3(4, 8, 8), 256, 0, stream>>>(Wv2, W2T + 16 * 32768, 256, 128);
    transpose_cast_kernel<<<dim3(8, 32, 1), 256, 0, stream>>>(Wo1, Wo1T, 1024, 256);
    transpose_cast_kernel<<<dim3(4, 8, 1), 256, 0, stream>>>(Wo2, Wo2T,  256, 128);
    prep_small_kernel<<<37, 256, 0, stream>>>(bq1, bk1, bv1, bq2, bk2, bv2, bo2, para,
                                              b1cat, b2cat, bo2p);

    // ---- phase A: q,k + scores, per chunk; units 0..15 batched in z ----
    {
        short* c1 = (short*)w;
        short* qk = (short*)(w + (size_t)NCA * 8192);
        for (int c = 0; c < N_NODES / NCA; ++c) {
            const int n0 = c * NCA;
            const short* smc = sm + (size_t)n0 * 256;
            gemm_bt_z<true, true><<<dim3(NCA / 128, 2, 16), 256, 0, stream>>>(
                smc, 256, 0, W1T, 65536, b1cat, 256, c1, 256, (long)NCA * 256, 256);
            gemm_bt_z<false, true><<<dim3(NCA / 128, 1, 16), 256, 0, stream>>>(
                c1, 256, (long)NCA * 256, W2T, 32768, b2cat, 128, qk, 2048, 128, 256);
            scores_mfma_kernel<<<NCA / 8, 256, 0, stream>>>(qk, scoresb + (size_t)n0 * 64, NCA);
        }
    }

    // ---- segment softmax stats (global) ----
    segstats_kernel<<<NSEG, 256, 0, stream>>>(scoresb, batch, segm, segdi);

    // ---- phase B: v + PV + out-MLP, per chunk; units 16..23 batched in z ----
    {
        short* c1 = (short*)w;                                   // also h2
        short* v  = (short*)(w + (size_t)NCB * 4096);
        short* s  = (short*)(w + (size_t)NCB * 4096 + (size_t)NCB * 2048);
        for (int c = 0; c < N_NODES / NCB; ++c) {
            const int n0 = c * NCB;
            const short* smc = sm + (size_t)n0 * 256;
            gemm_bt_z<true, true><<<dim3(NCB / 128, 2, 8), 256, 0, stream>>>(
                smc, 256, 0, W1T + 16 * 65536, 65536, b1cat + 16 * 256, 256,
                c1, 256, (long)NCB * 256, 256);
            gemm_bt_z<false, true><<<dim3(NCB / 128, 1, 8), 256, 0, stream>>>(
                c1, 256, (long)NCB * 256, W2T + 16 * 32768, 32768, b2cat + 16 * 128, 128,
                v, 1024, 128, 256);
            pv_kernel<<<NCB / 16, 256, 0, stream>>>(v, s, scoresb, batch, segm, segdi, n0);
            gemm_bt_z<true, true><<<dim3(NCB / 128, 2, 1), 256, 0, stream>>>(
                s, 1024, 0, Wo1T, 0, bo1, 0, c1, 256, 0, 1024);
            gemm_bt_z<false, false><<<dim3(NCB / 128, 1, 1), 256, 0, stream>>>(
                c1, 256, 0, Wo2T, 0, bo2p, 0, out + (size_t)n0 * 128, 128, 0, 256);
        }
    }
}